// Round 9
// baseline (260.114 us; speedup 1.0000x reference)
//
#include <hip/hip_runtime.h>
#include <math.h>

#define NB 4
#define NH 8
#define DD 64
#define LL 2048
#define CC 64
#define EPS 1e-5

typedef __attribute__((ext_vector_type(4))) float f32x4;
typedef __attribute__((ext_vector_type(8))) short bf16x8;
typedef __attribute__((ext_vector_type(2))) unsigned int u32x2;
typedef __attribute__((ext_vector_type(4))) unsigned int u32x4;

// truncate two f32 to bf16, pack to u32 (single v_perm)
__device__ __forceinline__ unsigned packtrunc(float a, float b) {
  return __builtin_amdgcn_perm(__builtin_bit_cast(unsigned, b),
                               __builtin_bit_cast(unsigned, a), 0x07060302u);
}
// round-to-nearest-even f32 -> bf16
__device__ __forceinline__ unsigned short f2bf(float f) {
  unsigned int u = __builtin_bit_cast(unsigned int, f);
  u += 0x7fffu + ((u >> 16) & 1u);
  return (unsigned short)(u >> 16);
}

__device__ __forceinline__ void reduce2_atomic(float s, float ss,
                                               double* dS, double* dSS,
                                               float* red, int nw) {
#pragma unroll
  for (int off = 32; off > 0; off >>= 1) {
    s += __shfl_xor(s, off);
    ss += __shfl_xor(ss, off);
  }
  const int t = threadIdx.x;
  if ((t & 63) == 0) { red[t >> 6] = s; red[8 + (t >> 6)] = ss; }
  __syncthreads();
  if (t == 0) {
    float S = 0.f, SS = 0.f;
    for (int w = 0; w < nw; ++w) { S += red[w]; SS += red[8 + w]; }
    atomicAdd(dS, (double)S);
    atomicAdd(dSS, (double)SS);
  }
}

// ---------- prep1: stage Q/K chunk, Gram partials -> d_out[8M,16M), colsums, kT bf16 -> d_out[0,8M) ----------
// grid 256 = 32 bh x 8 chunks(256 l), 256 thr
__global__ __launch_bounds__(256, 2) void prep1_kernel(
    const float* __restrict__ qg, const float* __restrict__ kg,
    float* __restrict__ colq, float* __restrict__ colk,
    float* __restrict__ gpart, unsigned short* __restrict__ kTout) {
  __shared__ short qs[64 * 256];  // [d][l] bf16, swizzle ^((d&7)<<3)
  __shared__ short ks[64 * 256];

  const int blk = blockIdx.x;
  const int bh = blk >> 3;
  const int ch = blk & 7;
  const int l0 = ch * 256;

  const float* qb = qg + (size_t)bh * DD * LL;
  const float* kb = kg + (size_t)bh * DD * LL;

  const int t = threadIdx.x;
  const int lane = t & 63;
  const int w = t >> 6;
  const int g = lane >> 4;
  const int ln = lane & 15;

  // ---- stage + column partial sums ----
  {
    const int d = t >> 2;
    const int lseg = (t & 3) * 64;
    const int swz = (d & 7) << 3;
    float pq = 0.f, pk = 0.f;
#pragma unroll
    for (int h = 0; h < 2; ++h) {
      f32x4 v[8];
#pragma unroll
      for (int j = 0; j < 8; ++j) v[j] = *(const f32x4*)&qb[(size_t)d * LL + l0 + lseg + h * 32 + j * 4];
#pragma unroll
      for (int j = 0; j < 8; ++j)
#pragma unroll
        for (int e = 0; e < 4; ++e) pq += v[j][e];
#pragma unroll
      for (int j2 = 0; j2 < 4; ++j2) {
        u32x4 wv = {packtrunc(v[2*j2][0], v[2*j2][1]), packtrunc(v[2*j2][2], v[2*j2][3]),
                    packtrunc(v[2*j2+1][0], v[2*j2+1][1]), packtrunc(v[2*j2+1][2], v[2*j2+1][3])};
        *(u32x4*)&qs[(d * 256 + lseg + h * 32 + j2 * 8) ^ swz] = wv;
      }
#pragma unroll
      for (int j = 0; j < 8; ++j) v[j] = *(const f32x4*)&kb[(size_t)d * LL + l0 + lseg + h * 32 + j * 4];
#pragma unroll
      for (int j = 0; j < 8; ++j)
#pragma unroll
        for (int e = 0; e < 4; ++e) pk += v[j][e];
#pragma unroll
      for (int j2 = 0; j2 < 4; ++j2) {
        u32x4 wv = {packtrunc(v[2*j2][0], v[2*j2][1]), packtrunc(v[2*j2][2], v[2*j2][3]),
                    packtrunc(v[2*j2+1][0], v[2*j2+1][1]), packtrunc(v[2*j2+1][2], v[2*j2+1][3])};
        *(u32x4*)&ks[(d * 256 + lseg + h * 32 + j2 * 8) ^ swz] = wv;
      }
    }
    pq += __shfl_xor(pq, 1); pq += __shfl_xor(pq, 2);
    pk += __shfl_xor(pk, 1); pk += __shfl_xor(pk, 2);
    if ((t & 3) == 0) {
      atomicAdd(&colq[bh * DD + d], pq);
      atomicAdd(&colk[bh * DD + d], pk);
    }
  }
  __syncthreads();

  // ---- Gram partials: wave w owns G rows [w*16, w*16+16) ----
  {
    f32x4 aq[4] = {{0,0,0,0},{0,0,0,0},{0,0,0,0},{0,0,0,0}};
    f32x4 ak[4] = {{0,0,0,0},{0,0,0,0},{0,0,0,0},{0,0,0,0}};
    const int ra = w * 16 + ln;
    const int swa = (ra & 7) << 3;
#pragma unroll
    for (int kc = 0; kc < 8; ++kc) {
      const int off = kc * 32 + g * 8;
      const bf16x8 faq = *(const bf16x8*)&qs[(ra * 256 + off) ^ swa];
      const bf16x8 fak = *(const bf16x8*)&ks[(ra * 256 + off) ^ swa];
#pragma unroll
      for (int tj = 0; tj < 4; ++tj) {
        const int rbr = tj * 16 + ln;
        const int swb = (rbr & 7) << 3;
        const bf16x8 fbq = *(const bf16x8*)&qs[(rbr * 256 + off) ^ swb];
        const bf16x8 fbk = *(const bf16x8*)&ks[(rbr * 256 + off) ^ swb];
        aq[tj] = __builtin_amdgcn_mfma_f32_16x16x32_bf16(faq, fbq, aq[tj], 0, 0, 0);
        ak[tj] = __builtin_amdgcn_mfma_f32_16x16x32_bf16(fak, fbk, ak[tj], 0, 0, 0);
      }
    }
    float* gq = gpart + (size_t)(bh * 8 + ch) * 8192;
    float* gk = gq + 4096;
#pragma unroll
    for (int tj = 0; tj < 4; ++tj)
#pragma unroll
      for (int r = 0; r < 4; ++r) {
        const int cell = (w * 16 + g * 4 + r) * 64 + tj * 16 + ln;
        gq[cell] = aq[tj][r];
        gk[cell] = ak[tj][r];
      }
  }

  // ---- K^T bf16 emit: thread t -> m-row (l0 + t) ----
  {
    unsigned short* dst = kTout + ((size_t)bh * LL + l0 + t) * DD;
#pragma unroll
    for (int g8 = 0; g8 < 8; ++g8) {
      unsigned u[4];
#pragma unroll
      for (int p = 0; p < 4; ++p) {
        const int d0 = g8 * 8 + p * 2;
        unsigned short s0 = (unsigned short)ks[(d0 * 256 + t) ^ ((d0 & 7) << 3)];
        unsigned short s1 = (unsigned short)ks[((d0 + 1) * 256 + t) ^ (((d0 + 1) & 7) << 3)];
        u[p] = (unsigned)s0 | ((unsigned)s1 << 16);
      }
      u32x4 wv = {u[0], u[1], u[2], u[3]};
      *(u32x4*)&dst[g8 * 8] = wv;
    }
  }
}

// ---------- copy kT (d_out[0,8M)) -> d_in[1][0,8M) ----------
__global__ __launch_bounds__(256) void copyk_kernel(const u32x4* __restrict__ src,
                                                    u32x4* __restrict__ dst) {
  const size_t i = (size_t)blockIdx.x * 256 + threadIdx.x;
  dst[i] = src[i];
}

// ---------- V f32 -> bf16 into d_in[1][8M,16M) ----------
__global__ __launch_bounds__(256) void vconv_kernel(const float* __restrict__ vg,
                                                    unsigned short* __restrict__ vB) {
  const size_t i = ((size_t)blockIdx.x * 256 + threadIdx.x) * 8;
  f32x4 a = *(const f32x4*)&vg[i];
  f32x4 b = *(const f32x4*)&vg[i + 4];
  u32x4 wv = {packtrunc(a[0], a[1]), packtrunc(a[2], a[3]),
              packtrunc(b[0], b[1]), packtrunc(b[2], b[3])};
  *(u32x4*)&vB[i] = wv;
}

// ---------- fin1: Sigma (Sigma_ch Gq) . (Sigma_ch Gk) per bh -> ssqd[b] ----------
__global__ __launch_bounds__(256) void fin1_kernel(const float* __restrict__ gpart,
                                                   double* __restrict__ ssqd) {
  __shared__ float red4[4];
  const int bh = blockIdx.x;
  const int t = threadIdx.x;
  const int lane = t & 63;
  f32x4 sq[4] = {{0,0,0,0},{0,0,0,0},{0,0,0,0},{0,0,0,0}};
  f32x4 sk[4] = {{0,0,0,0},{0,0,0,0},{0,0,0,0},{0,0,0,0}};
#pragma unroll 1
  for (int ch = 0; ch < 8; ++ch) {
    const float* pq = gpart + (size_t)(bh * 8 + ch) * 8192 + t * 16;
    const float* pk = pq + 4096;
#pragma unroll
    for (int i = 0; i < 4; ++i) {
      f32x4 a = *(const f32x4*)&pq[i * 4];
      f32x4 b = *(const f32x4*)&pk[i * 4];
#pragma unroll
      for (int e = 0; e < 4; ++e) { sq[i][e] += a[e]; sk[i][e] += b[e]; }
    }
  }
  float prod = 0.f;
#pragma unroll
  for (int i = 0; i < 4; ++i)
#pragma unroll
    for (int e = 0; e < 4; ++e) prod += sq[i][e] * sk[i][e];
#pragma unroll
  for (int off = 1; off < 64; off <<= 1) prod += __shfl_xor(prod, off);
  if (lane == 0) red4[t >> 6] = prod;
  __syncthreads();
  if (t == 0) atomicAdd(&ssqd[bh >> 3], (double)(red4[0] + red4[1] + red4[2] + red4[3]));
}

// ---------- fin2: per-batch logit scale (includes log2 e) ----------
__global__ void fin2_kernel(const double* __restrict__ ssqd,
                            const float* __restrict__ colq,
                            const float* __restrict__ colk,
                            float* __restrict__ scale2) {
  const int t = threadIdx.x, lane = t & 63, b = t >> 6;
  float part = 0.f;
#pragma unroll
  for (int j = 0; j < 8; ++j)
    part += colq[(b * 8 + j) * DD + lane] * colk[(b * 8 + j) * DD + lane];
#pragma unroll
  for (int off = 1; off < 64; off <<= 1) part += __shfl_xor(part, off);
  if (lane == 0) {
    const double cnt = 33554432.0;  // NH*LL*LL
    const double mu = (double)part / cnt;
    const double var = ssqd[b] / cnt - mu * mu;
    scale2[b] = (float)(1.4426950408889634 / sqrt(var + EPS));
  }
}

// ---------- attn: barrier-free flash attention; rv bf16 in-slot into d_out ----------
// grid 1024 = 32 bh x 32 l-blocks(64); 256 thr = 4 waves: (lg 0/1) x (mh 0/1).
__global__ __launch_bounds__(256, 3) void attn_kernel(
    const float* __restrict__ qg, const unsigned short* __restrict__ kT,
    const unsigned short* __restrict__ vB, unsigned short* __restrict__ outs,
    const float* __restrict__ scale2,
    double* __restrict__ s2, double* __restrict__ s2sq) {
  __shared__ short pb[4 * 2048];   // per-wave P [32][64] bf16, swizzled
  __shared__ float dbuf[2 * 512];  // per-pair dacc transfer
  __shared__ float red[16];

  const int phys = blockIdx.x;
  const int blk = ((phys & 7) << 7) | (phys >> 3);  // XCD-chunked, bijective (1024%8==0)
  const int bh = blk >> 5;
  const int lb = blk & 31;
  const int b = bh >> 3;
  const int l0b = lb * 64;

  const int t = threadIdx.x;
  const int lane = t & 63;
  const int wid = t >> 6;
  const int lg = wid >> 1;  // l-group (32 rows)
  const int mh = wid & 1;   // m-half (1024 m)
  const int g = lane >> 4;
  const int ln = lane & 15;

  const float* qbase = qg + (size_t)bh * DD * LL;
  const unsigned short* ktb = kT + (size_t)bh * LL * DD;
  const unsigned short* vbb = vB + (size_t)bh * CC * LL;
  const float sc2 = scale2[b];

  // Q fragments direct from global (scaled, trunc bf16)
  bf16x8 qf[2][2];
#pragma unroll
  for (int rb = 0; rb < 2; ++rb) {
    const int lq = l0b + lg * 32 + rb * 16 + ln;
#pragma unroll
    for (int kc = 0; kc < 2; ++kc) {
      float qv[8];
#pragma unroll
      for (int e = 0; e < 8; ++e)
        qv[e] = qbase[(size_t)(kc * 32 + g * 8 + e) * LL + lq] * sc2;
      u32x4 uq = {packtrunc(qv[0], qv[1]), packtrunc(qv[2], qv[3]),
                  packtrunc(qv[4], qv[5]), packtrunc(qv[6], qv[7])};
      qf[rb][kc] = __builtin_bit_cast(bf16x8, uq);
    }
  }

  short* pw = pb + wid * 2048;
  f32x4 o[2][4];
#pragma unroll
  for (int rb = 0; rb < 2; ++rb)
#pragma unroll
    for (int cf = 0; cf < 4; ++cf) o[rb][cf] = (f32x4){0.f, 0.f, 0.f, 0.f};
  f32x4 dacc[2] = {{0.f,0.f,0.f,0.f},{0.f,0.f,0.f,0.f}};

  const unsigned one2 = 0x3F803F80u;
  const u32x4 onesu = {one2, one2, one2, one2};
  const bf16x8 ones = __builtin_bit_cast(bf16x8, onesu);

#pragma unroll 1
  for (int it = 0; it < 16; ++it) {
    const int m0 = (mh * 16 + it) * 64;

    // V fragments (issued early; consumed after QK^T)
    bf16x8 vf[8];
#pragma unroll
    for (int mk = 0; mk < 2; ++mk)
#pragma unroll
      for (int cf = 0; cf < 4; ++cf) {
        const unsigned short* src = vbb + (size_t)(cf * 16 + ln) * LL + m0 + mk * 32 + g * 8;
        vf[mk * 4 + cf] = __builtin_bit_cast(bf16x8, *(const u32x4*)src);
      }

    // QK^T
    f32x4 s[2][4];
#pragma unroll
    for (int kc = 0; kc < 2; ++kc) {
      bf16x8 kf[4];
#pragma unroll
      for (int mf = 0; mf < 4; ++mf) {
        const unsigned short* src = ktb + (size_t)(m0 + mf * 16 + ln) * DD + kc * 32 + g * 8;
        kf[mf] = __builtin_bit_cast(bf16x8, *(const u32x4*)src);
      }
      __builtin_amdgcn_s_setprio(1);
#pragma unroll
      for (int mf = 0; mf < 4; ++mf) {
        if (kc == 0) {
          f32x4 z = {0.f, 0.f, 0.f, 0.f};
          s[0][mf] = __builtin_amdgcn_mfma_f32_16x16x32_bf16(kf[mf], qf[0][0], z, 0, 0, 0);
          s[1][mf] = __builtin_amdgcn_mfma_f32_16x16x32_bf16(kf[mf], qf[1][0], z, 0, 0, 0);
        } else {
          s[0][mf] = __builtin_amdgcn_mfma_f32_16x16x32_bf16(kf[mf], qf[0][1], s[0][mf], 0, 0, 0);
          s[1][mf] = __builtin_amdgcn_mfma_f32_16x16x32_bf16(kf[mf], qf[1][1], s[1][mf], 0, 0, 0);
        }
      }
      __builtin_amdgcn_s_setprio(0);
    }

    // P = exp2(s) (scale folded into Q), bf16 -> wave-private LDS
#pragma unroll
    for (int rb = 0; rb < 2; ++rb) {
      const int rr = rb * 16 + ln;
      const int swz = (rr & 7) << 3;
#pragma unroll
      for (int mf = 0; mf < 4; ++mf) {
        f32x4 p;
#pragma unroll
        for (int r = 0; r < 4; ++r) p[r] = __builtin_exp2f(s[rb][mf][r]);
        u32x2 wp = {packtrunc(p[0], p[1]), packtrunc(p[2], p[3])};
        *(u32x2*)&pw[(rr * 64 + mf * 16 + g * 4) ^ swz] = wp;
      }
    }
    asm volatile("s_waitcnt lgkmcnt(0)" ::: "memory");
    __builtin_amdgcn_sched_barrier(0);

    // PV + ones-denominator
    __builtin_amdgcn_s_setprio(1);
#pragma unroll
    for (int mk = 0; mk < 2; ++mk) {
      bf16x8 pf[2];
#pragma unroll
      for (int rb = 0; rb < 2; ++rb) {
        const int rr = rb * 16 + ln;
        pf[rb] = *(const bf16x8*)&pw[(rr * 64 + mk * 32 + g * 8) ^ ((rr & 7) << 3)];
      }
      dacc[0] = __builtin_amdgcn_mfma_f32_16x16x32_bf16(pf[0], ones, dacc[0], 0, 0, 0);
      dacc[1] = __builtin_amdgcn_mfma_f32_16x16x32_bf16(pf[1], ones, dacc[1], 0, 0, 0);
#pragma unroll
      for (int cf = 0; cf < 4; ++cf) {
        o[0][cf] = __builtin_amdgcn_mfma_f32_16x16x32_bf16(pf[0], vf[mk * 4 + cf], o[0][cf], 0, 0, 0);
        o[1][cf] = __builtin_amdgcn_mfma_f32_16x16x32_bf16(pf[1], vf[mk * 4 + cf], o[1][cf], 0, 0, 0);
      }
    }
    __builtin_amdgcn_s_setprio(0);
  }

  // ---- combine m-halves (barrier BEFORE reusing pb; fixed-max softmax -> pure add) ----
  __syncthreads();  // all waves done using pw
  float* ob = (float*)(pb + lg * 4096);  // 8KB slab per pair
  float* db = dbuf + lg * 512;
  if (mh == 1) {
#pragma unroll
    for (int rb = 0; rb < 2; ++rb) {
#pragma unroll
      for (int cf = 0; cf < 4; ++cf)
#pragma unroll
        for (int r = 0; r < 4; ++r)
          ob[((rb * 4 + cf) * 16 + g * 4 + r) * 16 + ln] = o[rb][cf][r];
#pragma unroll
      for (int r = 0; r < 4; ++r)
        db[(rb * 16 + g * 4 + r) * 16 + ln] = dacc[rb][r];
    }
  }
  __syncthreads();

  float ssum = 0.f, ssq = 0.f;
  if (mh == 0) {
#pragma unroll
    for (int rb = 0; rb < 2; ++rb) {
      float inv[4];
#pragma unroll
      for (int r = 0; r < 4; ++r)
        inv[r] = 1.0f / (dacc[rb][r] + db[(rb * 16 + g * 4 + r) * 16 + ln]);
      const int lbase = l0b + lg * 32 + rb * 16 + g * 4;
#pragma unroll
      for (int cf = 0; cf < 4; ++cf) {
        const size_t erow = ((size_t)(bh * CC + cf * 16 + ln)) * LL + lbase;
#pragma unroll
        for (int r = 0; r < 4; ++r) {
          const float x = (o[rb][cf][r] + ob[((rb * 4 + cf) * 16 + g * 4 + r) * 16 + ln]) * inv[r];
          ssum += x;
          ssq += x * x;
          outs[2 * (erow + r) + 1] = f2bf(x);  // in-slot bf16 (upper half of final f32 slot)
        }
      }
    }
  }
  __syncthreads();
  reduce2_atomic(ssum, ssq, &s2[b], &s2sq[b], red, 4);
}

// ---------- ln_gelu: read bf16 from own slot's upper half, write final f32 ----------
__global__ __launch_bounds__(256) void ln_gelu_kernel(
    float* __restrict__ out, const double* __restrict__ s2,
    const double* __restrict__ s2sq) {
  const size_t i = ((size_t)blockIdx.x * 256 + threadIdx.x) * 8;
  const int b = (int)(i >> 20);
  const double cnt = (double)(NH * CC) * (double)LL;
  const double mean = s2[b] / cnt;
  const double var = s2sq[b] / cnt - mean * mean;
  const float invs = (float)(1.0 / sqrt(var + EPS));
  const float mu = (float)mean;
  unsigned int* up = (unsigned int*)out;
  u32x4 a = *(const u32x4*)&up[i];
  u32x4 c = *(const u32x4*)&up[i + 4];
  f32x4 r0, r1;
#pragma unroll
  for (int j = 0; j < 4; ++j) {
    const float x = __builtin_bit_cast(float, a[j] & 0xFFFF0000u);
    const float z = (x - mu) * invs;
    r0[j] = 0.5f * z * (1.0f + erff(z * 0.70710678118f));
  }
#pragma unroll
  for (int j = 0; j < 4; ++j) {
    const float x = __builtin_bit_cast(float, c[j] & 0xFFFF0000u);
    const float z = (x - mu) * invs;
    r1[j] = 0.5f * z * (1.0f + erff(z * 0.70710678118f));
  }
  *(f32x4*)&out[i] = r0;
  *(f32x4*)&out[i + 4] = r1;
}

extern "C" void kernel_launch(void* const* d_in, const int* in_sizes, int n_in,
                              void* d_out, int out_size, void* d_ws, size_t ws_size,
                              hipStream_t stream) {
  (void)in_sizes; (void)n_in; (void)out_size; (void)ws_size;
  const float* q = (const float*)d_in[0];
  float* kbuf = (float*)d_in[1];          // K f32; reused as kT+vB scratch after prep1
  const float* v = (const float*)d_in[2];
  float* out = (float*)d_out;

  // small ws (16.5 KB total — proven safe)
  double* ssqd = (double*)d_ws;               // [4]
  double* ds2 = ssqd + 4;                     // [4]
  double* ds2sq = ssqd + 8;                   // [4]
  float* scale2 = (float*)(ssqd + 12);        // [4]
  float* colq = scale2 + 4;                   // [2048]
  float* colk = colq + 2048;                  // [2048]

  // d_out scratch: [0,8M) kT bf16 staging, [8M,16M) Gram partials
  unsigned short* kT_stage = (unsigned short*)out;
  float* gpart = out + 2097152;

  // d_in[1] scratch (K dead after prep1): [0,8M) kT, [8M,16M) vB
  unsigned short* kT = (unsigned short*)kbuf;
  unsigned short* vB = kT + 4194304;

  hipMemsetAsync(d_ws, 0, (12 + 4) * 8 + (4 + 4096) * 4, stream);

  prep1_kernel<<<dim3(256), dim3(256), 0, stream>>>(q, (const float*)kbuf, colq, colk, gpart, kT_stage);
  copyk_kernel<<<dim3(2048), dim3(256), 0, stream>>>((const u32x4*)kT_stage, (u32x4*)kT);
  vconv_kernel<<<dim3(2048), dim3(256), 0, stream>>>(v, vB);
  fin1_kernel<<<dim3(32), dim3(256), 0, stream>>>(gpart, ssqd);
  fin2_kernel<<<dim3(1), dim3(256), 0, stream>>>(ssqd, colq, colk, scale2);
  attn_kernel<<<dim3(1024), dim3(256), 0, stream>>>(q, kT, vB, (unsigned short*)out, scale2, ds2, ds2sq);
  ln_gelu_kernel<<<dim3(2048), dim3(256), 0, stream>>>(out, ds2, ds2sq);
}